// Round 5
// baseline (260.234 us; speedup 1.0000x reference)
//
#include <hip/hip_runtime.h>

typedef unsigned short u16;
typedef unsigned int u32;
typedef __attribute__((ext_vector_type(8))) short bf16x8;   // 8 bf16 in 4 VGPRs
typedef __attribute__((ext_vector_type(4))) float f32x4;

// ---------- bf16 helpers (RNE) ----------
__device__ __forceinline__ u16 f2bf(float f) {
  union { float f; u32 u; } v; v.f = f;
  u32 u = v.u;
  return (u16)((u + 0x7FFFu + ((u >> 16) & 1u)) >> 16);
}
__device__ __forceinline__ float bf2f(u16 s) {
  union { u32 u; float f; } v; v.u = ((u32)s) << 16;
  return v.f;
}

// ---------- async global->LDS (16B per lane) ----------
__device__ __forceinline__ void async16(const void* g, void* l) {
  __builtin_amdgcn_global_load_lds(
      (__attribute__((address_space(1))) void*)g,
      (__attribute__((address_space(3))) void*)l, 16, 0, 0);
}

// ---------- elementwise cast f32 -> bf16, 4 per thread ----------
__global__ void cast4_kernel(const float* __restrict__ in, u16* __restrict__ out, int n4) {
  int i = blockIdx.x * 256 + threadIdx.x;
  if (i < n4) {
    float4 v = ((const float4*)in)[i];
    ushort4 o;
    o.x = f2bf(v.x); o.y = f2bf(v.y); o.z = f2bf(v.z); o.w = f2bf(v.w);
    ((ushort4*)out)[i] = o;
  }
}

// ---------- transpose + cast 4 weights in one launch (z = which) ----------
__global__ void transpose_cast4_kernel(const float* __restrict__ W0, const float* __restrict__ W1,
                                       const float* __restrict__ W2, const float* __restrict__ W3,
                                       u16* __restrict__ O0, u16* __restrict__ O1,
                                       u16* __restrict__ O2, u16* __restrict__ O3) {
  const int R = 2048, C = 2048;
  const int z = blockIdx.z;
  const float* in = z == 0 ? W0 : z == 1 ? W1 : z == 2 ? W2 : W3;
  u16* out = z == 0 ? O0 : z == 1 ? O1 : z == 2 ? O2 : O3;
  __shared__ float tile[32][33];
  int c0 = blockIdx.x * 32, r0 = blockIdx.y * 32;
  int tx = threadIdx.x, ty = threadIdx.y;
#pragma unroll
  for (int i = ty; i < 32; i += 8) tile[i][tx] = in[(size_t)(r0 + i) * C + c0 + tx];
  __syncthreads();
#pragma unroll
  for (int i = ty; i < 32; i += 8)
    out[(size_t)(c0 + i) * R + r0 + tx] = f2bf(tile[tx][i]);
}

// ---------- cos/sin table from freqs (S x 64) ----------
__global__ void trig_kernel(const float* __restrict__ freqs, float* __restrict__ ct,
                            float* __restrict__ st, int n) {
  int i = blockIdx.x * 256 + threadIdx.x;
  if (i < n) { float f = freqs[i]; ct[i] = cosf(f); st[i] = sinf(f); }
}

// ---------- RoPE: q in-place; k read from kbf, rotated k written to Kp [h][s][128] ----------
__global__ void rope_kernel(u16* __restrict__ q, const u16* __restrict__ k,
                            u16* __restrict__ Kp,
                            const float* __restrict__ ct, const float* __restrict__ st) {
  int i = blockIdx.x * 256 + threadIdx.x;     // over S*H*32 = 2,097,152
  int dp = (i & 31) * 2;
  int hh = (i >> 5) & 15;
  int s  = i >> 9;
  float c0 = ct[s * 64 + dp], c1 = ct[s * 64 + dp + 1];
  float s0 = st[s * 64 + dp], s1 = st[s * 64 + dp + 1];
  size_t base = (size_t)s * 2048 + hh * 128 + dp;
  {
    u32 lo = *(u32*)(q + base);
    u32 hi = *(u32*)(q + base + 64);
    float a0 = bf2f((u16)lo), a1 = bf2f((u16)(lo >> 16));
    float b0 = bf2f((u16)hi), b1 = bf2f((u16)(hi >> 16));
    u32 nlo = (u32)f2bf(a0 * c0 - b0 * s0) | ((u32)f2bf(a1 * c1 - b1 * s1) << 16);
    u32 nhi = (u32)f2bf(b0 * c0 + a0 * s0) | ((u32)f2bf(b1 * c1 + a1 * s1) << 16);
    *(u32*)(q + base) = nlo;
    *(u32*)(q + base + 64) = nhi;
  }
  {
    u32 lo = *(const u32*)(k + base);
    u32 hi = *(const u32*)(k + base + 64);
    float a0 = bf2f((u16)lo), a1 = bf2f((u16)(lo >> 16));
    float b0 = bf2f((u16)hi), b1 = bf2f((u16)(hi >> 16));
    u32 nlo = (u32)f2bf(a0 * c0 - b0 * s0) | ((u32)f2bf(a1 * c1 - b1 * s1) << 16);
    u32 nhi = (u32)f2bf(b0 * c0 + a0 * s0) | ((u32)f2bf(b1 * c1 + a1 * s1) << 16);
    size_t kpb = ((size_t)hh * 4096 + s) * 128 + dp;
    *(u32*)(Kp + kpb) = nlo;
    *(u32*)(Kp + kpb + 64) = nhi;
  }
}

// ---------- V repack: vbf (S, H*HD) -> VT2 [h][tile][d 0..127][key 0..15] ----------
__global__ void repack_v_kernel(const u16* __restrict__ Vin, u16* __restrict__ VT2) {
  const int h = blockIdx.y;
  const int s0 = blockIdx.x * 64;      // 4 tiles per block
  const int tid = threadIdx.x;
  __shared__ u16 lv[64][132];          // 64 tokens x 128 dims (+4 pad)
#pragma unroll
  for (int i = 0; i < 16; ++i) {
    int idx = i * 256 + tid;
    int r = idx >> 6;
    int d2 = idx & 63;
    u32 vv = ((const u32*)Vin)[(size_t)(s0 + r) * 1024 + h * 64 + d2];
    *(u32*)(&lv[r][d2 * 2]) = vv;
  }
  __syncthreads();
#pragma unroll
  for (int i = 0; i < 16; ++i) {
    int idx = i * 256 + tid;           // 0..4095
    int k2 = idx & 7;                  // u32 over 2 keys
    int d  = (idx >> 3) & 127;
    int tl = idx >> 10;                // local tile 0..3
    u32 lo = lv[tl * 16 + k2 * 2][d];
    u32 hi = lv[tl * 16 + k2 * 2 + 1][d];
    ((u32*)VT2)[(((size_t)h * 256 + blockIdx.x * 4 + tl) * 128 + d) * 8 + k2] = lo | (hi << 16);
  }
}

// ---------- bf16 GEMM: C(MxN) = A(MxK) * Bt(NxK)^T, f32 accumulate ----------
// 128x128 tile, BK=64, 4 waves (2x2), 2 blocks/CU. Double-buffered LDS with
// single raw s_barrier per K-tile: stage(t+1) issued BEFORE compute(t), so the
// vmcnt(0) drain sits behind ~500cy of MFMA. setprio around MFMA cluster.
// MODE 0: f32 out. MODE 1: bf16 out. MODE 2: QKV-fused routing by col block.
template <int MODE>
__launch_bounds__(256, 2)
__global__ void gemm128_kernel(const u16* __restrict__ A, const u16* __restrict__ Bt,
                               void* __restrict__ C, u16* __restrict__ D1, u16* __restrict__ D2,
                               int M, int N, int K) {
  __shared__ __align__(16) u16 As[2][128 * 64];   // 32 KB
  __shared__ __align__(16) u16 Bs[2][128 * 64];   // 32 KB
  const int tid  = threadIdx.x;
  const int lane = tid & 63;
  const int wave = tid >> 6;
  const int wr = wave >> 1, wc = wave & 1;

  // bijective XCD swizzle (requires nwg % 8 == 0); column-major decompose so
  // one XCD's blocks share consecutive col panels (B L2-resident).
  const int nbx = gridDim.x, nby = gridDim.y;
  const int nwg = nbx * nby;
  const int bid = blockIdx.y * nbx + blockIdx.x;
  const int sbid = (bid & 7) * (nwg >> 3) + (bid >> 3);
  const int bx = sbid / nby;
  const int by = sbid % nby;
  const int brow = by * 128;
  const int bcol = bx * 128;

  int a_goff[4], b_goff[4], l_off[4];
#pragma unroll
  for (int i = 0; i < 4; ++i) {
    int p = (wave * 4 + i) * 1024 + lane * 16;        // linear byte in 16KB tile
    int row = p >> 7;                                 // 128B per row (64 bf16)
    int colb = (p & 127) ^ ((row & 7) << 4);          // inverse swizzle on source
    a_goff[i] = (brow + row) * K + (colb >> 1);
    b_goff[i] = (bcol + row) * K + (colb >> 1);
    l_off[i] = p;
  }

  f32x4 acc[4][4];
#pragma unroll
  for (int m = 0; m < 4; ++m)
#pragma unroll
    for (int n = 0; n < 4; ++n) acc[m][n] = (f32x4){0.f, 0.f, 0.f, 0.f};

  auto stage = [&](int bufi, int k0) {
#pragma unroll
    for (int i = 0; i < 4; ++i) {
      async16(A + a_goff[i] + k0, (char*)As[bufi] + l_off[i]);
      async16(Bt + b_goff[i] + k0, (char*)Bs[bufi] + l_off[i]);
    }
  };

  const int nt = K >> 6;
  // prologue: stage tile 0, drain, sync
  stage(0, 0);
  asm volatile("s_waitcnt vmcnt(0)" ::: "memory");
  __builtin_amdgcn_s_barrier();
  __builtin_amdgcn_sched_barrier(0);

  for (int t = 0; t < nt; ++t) {
    const int b = t & 1;
    if (t + 1 < nt) stage(b ^ 1, (t + 1) << 6);   // issue next tile's 8 loads first
#pragma unroll
    for (int kk = 0; kk < 2; ++kk) {
      bf16x8 af[4], bfr[4];
#pragma unroll
      for (int m = 0; m < 4; ++m) {
        int row = wr * 64 + m * 16 + (lane & 15);
        int byte = (row << 7) + ((kk * 64 + ((lane >> 4) << 4)) ^ ((row & 7) << 4));
        af[m] = *(const bf16x8*)((const char*)As[b] + byte);
      }
#pragma unroll
      for (int n = 0; n < 4; ++n) {
        int row = wc * 64 + n * 16 + (lane & 15);
        int byte = (row << 7) + ((kk * 64 + ((lane >> 4) << 4)) ^ ((row & 7) << 4));
        bfr[n] = *(const bf16x8*)((const char*)Bs[b] + byte);
      }
      __builtin_amdgcn_s_setprio(1);
#pragma unroll
      for (int m = 0; m < 4; ++m)
#pragma unroll
        for (int n = 0; n < 4; ++n)
          acc[m][n] = __builtin_amdgcn_mfma_f32_16x16x32_bf16(af[m], bfr[n], acc[m][n], 0, 0, 0);
      __builtin_amdgcn_s_setprio(0);
    }
    // next tile's loads had the whole compute to land; drain + one barrier.
    asm volatile("s_waitcnt vmcnt(0)" ::: "memory");
    __builtin_amdgcn_s_barrier();
    __builtin_amdgcn_sched_barrier(0);
  }

  const int r0 = brow + wr * 64;
  const int c0 = bcol + wc * 64;
  if (MODE == 2) {
    const int sel = bcol >> 11;                       // block-uniform
    u16* dst = sel == 0 ? (u16*)C : sel == 1 ? D1 : D2;
    const int c0l = (bcol & 2047) + wc * 64;
#pragma unroll
    for (int m = 0; m < 4; ++m)
#pragma unroll
      for (int n = 0; n < 4; ++n)
#pragma unroll
        for (int r = 0; r < 4; ++r) {
          int rr = r0 + m * 16 + ((lane >> 4) << 2) + r;
          int cc = c0l + n * 16 + (lane & 15);
          dst[(size_t)rr * 2048 + cc] = f2bf(acc[m][n][r]);
        }
  } else {
#pragma unroll
    for (int m = 0; m < 4; ++m)
#pragma unroll
      for (int n = 0; n < 4; ++n)
#pragma unroll
        for (int r = 0; r < 4; ++r) {
          int rr = r0 + m * 16 + ((lane >> 4) << 2) + r;
          int cc = c0 + n * 16 + (lane & 15);
          if (MODE == 1) ((u16*)C)[(size_t)rr * N + cc] = f2bf(acc[m][n][r]);
          else           ((float*)C)[(size_t)rr * N + cc] = acc[m][n][r];
        }
  }
}

// ---------- sparse tile attention: one block per (tile t, head h) ----------
// 17 key tiles (16 anchors + local) padded to 20; 272 keys padded to 288 with
// zero weights. K from Kp [h][s][128]; V from VT2 [h][tile][d][16].
// bf16 softmax weights OVERLAY the f32 logits buffer row-aligned (each 1168B
// row holds its own 576B of weights; within-wave lockstep + per-row ownership
// make read-then-overwrite safe). LDS ~18.8KB -> 6 blocks/CU.
__launch_bounds__(256, 6)
__global__ void attn_kernel(const u16* __restrict__ Q, const u16* __restrict__ Kp,
                            const u16* __restrict__ VT2, const int* __restrict__ anchors,
                            u16* __restrict__ Out) {
  const int t = blockIdx.x;   // 0..255
  const int h = blockIdx.y;   // 0..15
  __shared__ int tiles[20];
  __shared__ __align__(16) float lg[16][292];    // logits; weights overlay per-row
  const int tid  = threadIdx.x;
  const int lane = tid & 63;
  const int wave = tid >> 6;
  const int g = lane >> 4;          // k-group 0..3
  const int c = lane & 15;

  if (tid < 16) tiles[tid] = anchors[(size_t)((h << 12) + (t * 16 + 15)) * 16 + tid];
  if (tid == 16) tiles[16] = t;            // local tile (order: anchors then local)
  if (tid >= 17 && tid < 20) tiles[tid] = 0;   // dummy tiles (results discarded)
  __syncthreads();

  // ---- QK: Q(16x128) . K_tile(16x128)^T; 5 fixed iters/wave, 1-ahead prefetch
  {
    const u16* qbase = Q + (size_t)(t * 16 + c) * 2048 + h * 128 + g * 8;
    bf16x8 qf[4];
#pragma unroll
    for (int ks = 0; ks < 4; ++ks) qf[ks] = *(const bf16x8*)(qbase + ks * 32);

    int tok_[5];
    const u16* kb_[5];
#pragma unroll
    for (int i = 0; i < 5; ++i) {
      int j = wave + 4 * i;                  // < 20
      tok_[i] = tiles[j] * 16 + c;
      kb_[i] = Kp + ((size_t)h * 4096 + tok_[i]) * 128 + g * 8;
    }
    bf16x8 kfp[2][4];
#pragma unroll
    for (int ks = 0; ks < 4; ++ks) kfp[0][ks] = *(const bf16x8*)(kb_[0] + ks * 32);
#pragma unroll
    for (int i = 0; i < 5; ++i) {
      if (i < 4) {
#pragma unroll
        for (int ks = 0; ks < 4; ++ks)
          kfp[(i + 1) & 1][ks] = *(const bf16x8*)(kb_[i + 1] + ks * 32);
      }
      f32x4 a = (f32x4){0.f, 0.f, 0.f, 0.f};
#pragma unroll
      for (int ks = 0; ks < 4; ++ks)
        a = __builtin_amdgcn_mfma_f32_16x16x32_bf16(qf[ks], kfp[i & 1][ks], a, 0, 0, 0);
      int j = wave + 4 * i;
      if (j < 17) {
#pragma unroll
        for (int r = 0; r < 4; ++r) {
          int qrow = g * 4 + r;
          float vv = a[r] * 0.088388347648318447f;   // 1/sqrt(128)
          if (tok_[i] > t * 16 + qrow) vv = -1e10f;  // future mask
          lg[qrow][j * 16 + c] = vv;
        }
      }
    }
  }
  __syncthreads();

  // ---- softmax per q row: row r handled by 16 threads (col = tid&15);
  // bf16 weights written over the row's own f32 storage (reads complete first
  // in lockstep; each wave touches only its own 4 rows).
  {
    const int r = tid >> 4, cc = tid & 15;
    float vals[17];
    float mx = -3.0e38f;
#pragma unroll
    for (int i = 0; i < 17; ++i) { vals[i] = lg[r][i * 16 + cc]; mx = fmaxf(mx, vals[i]); }
#pragma unroll
    for (int d = 1; d < 16; d <<= 1) mx = fmaxf(mx, __shfl_xor(mx, d, 64));
    float sum = 0.f;
#pragma unroll
    for (int i = 0; i < 17; ++i) { vals[i] = __expf(vals[i] - mx); sum += vals[i]; }
#pragma unroll
    for (int d = 1; d < 16; d <<= 1) sum += __shfl_xor(sum, d, 64);
    float inv = sum > 0.f ? 1.0f / sum : 0.f;
    u16* wrow = (u16*)&lg[r][0];
#pragma unroll
    for (int i = 0; i < 17; ++i) wrow[i * 16 + cc] = f2bf(vals[i] * inv);
    wrow[272 + cc] = 0;                        // zero the pad tile's weights
  }
  __syncthreads();

  // ---- PV: out(16x288 . 288x128); wave owns 32 dims; 1-ahead B-pair prefetch
  {
    f32x4 o0 = (f32x4){0.f, 0.f, 0.f, 0.f}, o1 = o0;
    const int d0 = wave * 32;
    const size_t hb = (size_t)h * 256;
    const int keyin = (g & 1) * 8;
    const u16* wrow = (const u16*)&lg[c][0];
    const u16* vb_[9];
#pragma unroll
    for (int ks = 0; ks < 9; ++ks) vb_[ks] = VT2 + (hb + tiles[2 * ks + (g >> 1)]) * 2048;
    bf16x8 pb0[2], pb1[2];
    pb0[0] = *(const bf16x8*)(vb_[0] + (d0 + c) * 16 + keyin);
    pb1[0] = *(const bf16x8*)(vb_[0] + (d0 + 16 + c) * 16 + keyin);
#pragma unroll
    for (int ks = 0; ks < 9; ++ks) {
      if (ks < 8) {
        pb0[(ks + 1) & 1] = *(const bf16x8*)(vb_[ks + 1] + (d0 + c) * 16 + keyin);
        pb1[(ks + 1) & 1] = *(const bf16x8*)(vb_[ks + 1] + (d0 + 16 + c) * 16 + keyin);
      }
      bf16x8 af = *(const bf16x8*)(wrow + ks * 32 + g * 8);
      o0 = __builtin_amdgcn_mfma_f32_16x16x32_bf16(af, pb0[ks & 1], o0, 0, 0, 0);
      o1 = __builtin_amdgcn_mfma_f32_16x16x32_bf16(af, pb1[ks & 1], o1, 0, 0, 0);
    }
#pragma unroll
    for (int r = 0; r < 4; ++r) {
      int qrow = g * 4 + r;
      size_t base = (size_t)(t * 16 + qrow) * 2048 + h * 128;
      Out[base + d0 + c]      = f2bf(o0[r]);
      Out[base + d0 + 16 + c] = f2bf(o1[r]);
    }
  }
}

extern "C" void kernel_launch(void* const* d_in, const int* in_sizes, int n_in,
                              void* d_out, int out_size, void* d_ws, size_t ws_size,
                              hipStream_t stream) {
  (void)in_sizes; (void)n_in; (void)out_size; (void)ws_size;
  const float* x      = (const float*)d_in[0];
  const float* Wq     = (const float*)d_in[1];
  const float* Wk     = (const float*)d_in[2];
  const float* Wv     = (const float*)d_in[3];
  const float* Wo     = (const float*)d_in[4];
  const float* freqs  = (const float*)d_in[5];
  const int* anchors  = (const int*)d_in[6];
  float* out = (float*)d_out;

  char* ws = (char*)d_ws;
  const size_t MB = 1024 * 1024;
  // Layout (96 MB total, aliasing dead buffers):
  //  0..16  : xbf, later attnb (x dead after QKV GEMM)
  // 16..40  : wqkvT contiguous (wqT 16..24, wkT 24..32, wvT 32..40);
  //           later Kp over 16..32 (dead after QKV GEMM), ct/st over 32..34
  // 40..48  : woT (live until final GEMM)
  // 48..64  : qbf
  // 64..80  : kbf; later VT2 (kbf dead after rope writes Kp)
  // 80..96  : vbf
  u16* xbf   = (u16*)(ws + 0);
  u16* wqkvT = (u16*)(ws + 16 * MB);   // (6144 x 2048) bf16, N x K
  u16* woT   = (u16*)(ws + 40 * MB);
  u16* qbf   = (u16*)(ws + 48 * MB);
  u16* kbf   = (u16*)(ws + 64 * MB);
  u16* vbf   = (u16*)(ws + 80 * MB);
  u16* attnb = (u16*)(ws + 0);
  u16* Kp    = (u16*)(ws + 16 * MB);
  float* ct  = (float*)(ws + 32 * MB);
  float* st  = (float*)(ws + 33 * MB);
  u16* VT2   = (u16*)(ws + 64 * MB);

  cast4_kernel<<<8192, 256, 0, stream>>>(x, xbf, 2097152);
  dim3 tb(32, 8), tg4(64, 64, 4);
  transpose_cast4_kernel<<<tg4, tb, 0, stream>>>(
      Wq, Wk, Wv, Wo,
      wqkvT, wqkvT + (size_t)8 * MB / 2, wqkvT + (size_t)16 * MB / 2, woT);

  // fused QKV projection: C = x(4096x2048) @ WqkvT(6144x2048)^T, routed epilogue
  gemm128_kernel<2><<<dim3(48, 32), 256, 0, stream>>>(xbf, wqkvT, qbf, kbf, vbf,
                                                      4096, 6144, 2048);
  trig_kernel<<<1024, 256, 0, stream>>>(freqs, ct, st, 262144);   // over dead wvT
  rope_kernel<<<8192, 256, 0, stream>>>(qbf, kbf, Kp, ct, st);    // k -> Kp directly
  repack_v_kernel<<<dim3(64, 16), 256, 0, stream>>>(vbf, VT2);    // over dead kbf
  attn_kernel<<<dim3(256, 16), 256, 0, stream>>>(qbf, Kp, VT2, anchors, attnb);
  gemm128_kernel<0><<<dim3(16, 32), 256, 0, stream>>>(attnb, woT, out, nullptr, nullptr,
                                                      4096, 2048, 2048);
}

// Round 6
// 240.964 us; speedup vs baseline: 1.0800x; 1.0800x over previous
//
#include <hip/hip_runtime.h>

typedef unsigned short u16;
typedef unsigned int u32;
typedef __attribute__((ext_vector_type(8))) short bf16x8;   // 8 bf16 in 4 VGPRs
typedef __attribute__((ext_vector_type(4))) float f32x4;

// ---------- bf16 helpers (RNE) ----------
__device__ __forceinline__ u16 f2bf(float f) {
  union { float f; u32 u; } v; v.f = f;
  u32 u = v.u;
  return (u16)((u + 0x7FFFu + ((u >> 16) & 1u)) >> 16);
}
__device__ __forceinline__ float bf2f(u16 s) {
  union { u32 u; float f; } v; v.u = ((u32)s) << 16;
  return v.f;
}

// ---------- async global->LDS (16B per lane) ----------
__device__ __forceinline__ void async16(const void* g, void* l) {
  __builtin_amdgcn_global_load_lds(
      (__attribute__((address_space(1))) void*)g,
      (__attribute__((address_space(3))) void*)l, 16, 0, 0);
}

// ---------- prep1: fused {4x weight transpose+cast, x cast, trig table} ----------
// flat grid, 256 thr: blocks [0,16384) transpose (4096/weight), [16384,24576)
// cast x (4 f32->bf16 per thread), [24576,25600) cos/sin table.
__global__ void prep1_kernel(const float* __restrict__ x,
                             const float* __restrict__ W0, const float* __restrict__ W1,
                             const float* __restrict__ W2, const float* __restrict__ W3,
                             const float* __restrict__ freqs,
                             u16* __restrict__ xbf, u16* __restrict__ wqkvT,
                             u16* __restrict__ woT,
                             float* __restrict__ ct, float* __restrict__ st) {
  __shared__ float tile[32][33];
  const int bid = blockIdx.x;
  const int tid = threadIdx.x;
  if (bid < 16384) {
    const int z = bid >> 12;
    const float* in = z == 0 ? W0 : z == 1 ? W1 : z == 2 ? W2 : W3;
    u16* out = z == 3 ? woT : wqkvT + (size_t)z * 4194304;
    const int local = bid & 4095;
    const int c0 = (local & 63) * 32, r0 = (local >> 6) * 32;
    const int tx = tid & 31, ty = tid >> 5;
#pragma unroll
    for (int i = ty; i < 32; i += 8) tile[i][tx] = in[(size_t)(r0 + i) * 2048 + c0 + tx];
    __syncthreads();
#pragma unroll
    for (int i = ty; i < 32; i += 8)
      out[(size_t)(c0 + i) * 2048 + r0 + tx] = f2bf(tile[tx][i]);
  } else if (bid < 24576) {
    int i = (bid - 16384) * 256 + tid;     // < 2097152
    float4 v = ((const float4*)x)[i];
    ushort4 o;
    o.x = f2bf(v.x); o.y = f2bf(v.y); o.z = f2bf(v.z); o.w = f2bf(v.w);
    ((ushort4*)xbf)[i] = o;
  } else {
    int i = (bid - 24576) * 256 + tid;     // < 262144
    float f = freqs[i];
    ct[i] = cosf(f); st[i] = sinf(f);
  }
}

// ---------- prep2: fused {RoPE (q in-place, k->Kp), V repack -> VT2} ----------
// blocks [0,8192) rope; [8192,9216) repack_v (local: s-block = &63, h = >>6).
__global__ void prep2_kernel(u16* __restrict__ q, const u16* __restrict__ k,
                             u16* __restrict__ Kp,
                             const u16* __restrict__ Vin, u16* __restrict__ VT2,
                             const float* __restrict__ ct, const float* __restrict__ st) {
  __shared__ u16 lv[64][132];
  const int bid = blockIdx.x;
  const int tid = threadIdx.x;
  if (bid < 8192) {
    int i = bid * 256 + tid;                  // over S*H*32 = 2,097,152
    int dp = (i & 31) * 2;
    int hh = (i >> 5) & 15;
    int s  = i >> 9;
    float c0 = ct[s * 64 + dp], c1 = ct[s * 64 + dp + 1];
    float s0 = st[s * 64 + dp], s1 = st[s * 64 + dp + 1];
    size_t base = (size_t)s * 2048 + hh * 128 + dp;
    {
      u32 lo = *(u32*)(q + base);
      u32 hi = *(u32*)(q + base + 64);
      float a0 = bf2f((u16)lo), a1 = bf2f((u16)(lo >> 16));
      float b0 = bf2f((u16)hi), b1 = bf2f((u16)(hi >> 16));
      u32 nlo = (u32)f2bf(a0 * c0 - b0 * s0) | ((u32)f2bf(a1 * c1 - b1 * s1) << 16);
      u32 nhi = (u32)f2bf(b0 * c0 + a0 * s0) | ((u32)f2bf(b1 * c1 + a1 * s1) << 16);
      *(u32*)(q + base) = nlo;
      *(u32*)(q + base + 64) = nhi;
    }
    {
      u32 lo = *(const u32*)(k + base);
      u32 hi = *(const u32*)(k + base + 64);
      float a0 = bf2f((u16)lo), a1 = bf2f((u16)(lo >> 16));
      float b0 = bf2f((u16)hi), b1 = bf2f((u16)(hi >> 16));
      u32 nlo = (u32)f2bf(a0 * c0 - b0 * s0) | ((u32)f2bf(a1 * c1 - b1 * s1) << 16);
      u32 nhi = (u32)f2bf(b0 * c0 + a0 * s0) | ((u32)f2bf(b1 * c1 + a1 * s1) << 16);
      size_t kpb = ((size_t)hh * 4096 + s) * 128 + dp;
      *(u32*)(Kp + kpb) = nlo;
      *(u32*)(Kp + kpb + 64) = nhi;
    }
  } else {
    const int local = bid - 8192;             // 0..1023
    const int h = local >> 6;
    const int s0 = (local & 63) * 64;         // 4 tiles per block
#pragma unroll
    for (int i = 0; i < 16; ++i) {
      int idx = i * 256 + tid;
      int r = idx >> 6;
      int d2 = idx & 63;
      u32 vv = ((const u32*)Vin)[(size_t)(s0 + r) * 1024 + h * 64 + d2];
      *(u32*)(&lv[r][d2 * 2]) = vv;
    }
    __syncthreads();
#pragma unroll
    for (int i = 0; i < 16; ++i) {
      int idx = i * 256 + tid;               // 0..4095
      int k2 = idx & 7;                      // u32 over 2 keys
      int d  = (idx >> 3) & 127;
      int tl = idx >> 10;                    // local tile 0..3
      u32 lo = lv[tl * 16 + k2 * 2][d];
      u32 hi = lv[tl * 16 + k2 * 2 + 1][d];
      ((u32*)VT2)[(((size_t)h * 256 + (s0 >> 4) + tl) * 128 + d) * 8 + k2] = lo | (hi << 16);
    }
  }
}

// ---------- bf16 GEMM: C(MxN) = A(MxK) * Bt(NxK)^T, f32 accumulate ----------
// Proven structure (round 4: 1065 TF, MfmaUtil 49%): 128x128 tile, BK=64,
// 4 waves (2x2), single-buffer 32KB LDS, two __syncthreads per K-tile.
// MODE 0: f32 out. MODE 1: bf16 out. MODE 2: QKV-fused routing by col block.
template <int MODE>
__launch_bounds__(256, 2)
__global__ void gemm128_kernel(const u16* __restrict__ A, const u16* __restrict__ Bt,
                               void* __restrict__ C, u16* __restrict__ D1, u16* __restrict__ D2,
                               int M, int N, int K) {
  __shared__ __align__(16) u16 As[128 * 64];
  __shared__ __align__(16) u16 Bs[128 * 64];
  const int tid  = threadIdx.x;
  const int lane = tid & 63;
  const int wave = tid >> 6;
  const int wr = wave >> 1, wc = wave & 1;
  const int brow = blockIdx.y * 128;
  const int bcol = blockIdx.x * 128;

  int a_goff[4], b_goff[4], l_off[4];
#pragma unroll
  for (int i = 0; i < 4; ++i) {
    int p = (wave * 4 + i) * 1024 + lane * 16;        // linear byte in 16KB tile
    int row = p >> 7;                                 // 128B per row (64 bf16)
    int colb = (p & 127) ^ ((row & 7) << 4);          // inverse swizzle on source
    a_goff[i] = (brow + row) * K + (colb >> 1);
    b_goff[i] = (bcol + row) * K + (colb >> 1);
    l_off[i] = p;
  }

  f32x4 acc[4][4];
#pragma unroll
  for (int m = 0; m < 4; ++m)
#pragma unroll
    for (int n = 0; n < 4; ++n) acc[m][n] = (f32x4){0.f, 0.f, 0.f, 0.f};

  for (int k0 = 0; k0 < K; k0 += 64) {
#pragma unroll
    for (int i = 0; i < 4; ++i) {
      async16(A + a_goff[i] + k0, (char*)As + l_off[i]);
      async16(Bt + b_goff[i] + k0, (char*)Bs + l_off[i]);
    }
    __syncthreads();
#pragma unroll
    for (int kk = 0; kk < 2; ++kk) {
      bf16x8 af[4], bfr[4];
#pragma unroll
      for (int m = 0; m < 4; ++m) {
        int row = wr * 64 + m * 16 + (lane & 15);
        int byte = (row << 7) + ((kk * 64 + ((lane >> 4) << 4)) ^ ((row & 7) << 4));
        af[m] = *(const bf16x8*)((const char*)As + byte);
      }
#pragma unroll
      for (int n = 0; n < 4; ++n) {
        int row = wc * 64 + n * 16 + (lane & 15);
        int byte = (row << 7) + ((kk * 64 + ((lane >> 4) << 4)) ^ ((row & 7) << 4));
        bfr[n] = *(const bf16x8*)((const char*)Bs + byte);
      }
#pragma unroll
      for (int m = 0; m < 4; ++m)
#pragma unroll
        for (int n = 0; n < 4; ++n)
          acc[m][n] = __builtin_amdgcn_mfma_f32_16x16x32_bf16(af[m], bfr[n], acc[m][n], 0, 0, 0);
    }
    __syncthreads();
  }

  const int r0 = brow + wr * 64;
  const int c0 = bcol + wc * 64;
  if (MODE == 2) {
    const int sel = bcol >> 11;                       // block-uniform
    u16* dst = sel == 0 ? (u16*)C : sel == 1 ? D1 : D2;
    const int c0l = (bcol & 2047) + wc * 64;
#pragma unroll
    for (int m = 0; m < 4; ++m)
#pragma unroll
      for (int n = 0; n < 4; ++n)
#pragma unroll
        for (int r = 0; r < 4; ++r) {
          int rr = r0 + m * 16 + ((lane >> 4) << 2) + r;
          int cc = c0l + n * 16 + (lane & 15);
          dst[(size_t)rr * 2048 + cc] = f2bf(acc[m][n][r]);
        }
  } else {
#pragma unroll
    for (int m = 0; m < 4; ++m)
#pragma unroll
      for (int n = 0; n < 4; ++n)
#pragma unroll
        for (int r = 0; r < 4; ++r) {
          int rr = r0 + m * 16 + ((lane >> 4) << 2) + r;
          int cc = c0 + n * 16 + (lane & 15);
          if (MODE == 1) ((u16*)C)[(size_t)rr * N + cc] = f2bf(acc[m][n][r]);
          else           ((float*)C)[(size_t)rr * N + cc] = acc[m][n][r];
        }
  }
}

// ---------- sparse tile attention: one block per (tile t, head h) ----------
// 17 key tiles (16 anchors + local) padded to 20; 272 keys padded to 288 with
// zero weights. K from Kp [h][s][128]; V from VT2 [h][tile][d][16].
// bf16 softmax weights OVERLAY the f32 logits buffer row-aligned (each 1168B
// row holds its own 576B of weights; within-wave lockstep + per-row ownership
// make read-then-overwrite safe). LDS ~18.8KB -> 6 blocks/CU.
__launch_bounds__(256, 6)
__global__ void attn_kernel(const u16* __restrict__ Q, const u16* __restrict__ Kp,
                            const u16* __restrict__ VT2, const int* __restrict__ anchors,
                            u16* __restrict__ Out) {
  const int t = blockIdx.x;   // 0..255
  const int h = blockIdx.y;   // 0..15
  __shared__ int tiles[20];
  __shared__ __align__(16) float lg[16][292];    // logits; weights overlay per-row
  const int tid  = threadIdx.x;
  const int lane = tid & 63;
  const int wave = tid >> 6;
  const int g = lane >> 4;          // k-group 0..3
  const int c = lane & 15;

  if (tid < 16) tiles[tid] = anchors[(size_t)((h << 12) + (t * 16 + 15)) * 16 + tid];
  if (tid == 16) tiles[16] = t;            // local tile (order: anchors then local)
  if (tid >= 17 && tid < 20) tiles[tid] = 0;   // dummy tiles (results discarded)
  __syncthreads();

  // ---- QK: Q(16x128) . K_tile(16x128)^T; 5 fixed iters/wave, 1-ahead prefetch
  {
    const u16* qbase = Q + (size_t)(t * 16 + c) * 2048 + h * 128 + g * 8;
    bf16x8 qf[4];
#pragma unroll
    for (int ks = 0; ks < 4; ++ks) qf[ks] = *(const bf16x8*)(qbase + ks * 32);

    int tok_[5];
    const u16* kb_[5];
#pragma unroll
    for (int i = 0; i < 5; ++i) {
      int j = wave + 4 * i;                  // < 20
      tok_[i] = tiles[j] * 16 + c;
      kb_[i] = Kp + ((size_t)h * 4096 + tok_[i]) * 128 + g * 8;
    }
    bf16x8 kfp[2][4];
#pragma unroll
    for (int ks = 0; ks < 4; ++ks) kfp[0][ks] = *(const bf16x8*)(kb_[0] + ks * 32);
#pragma unroll
    for (int i = 0; i < 5; ++i) {
      if (i < 4) {
#pragma unroll
        for (int ks = 0; ks < 4; ++ks)
          kfp[(i + 1) & 1][ks] = *(const bf16x8*)(kb_[i + 1] + ks * 32);
      }
      f32x4 a = (f32x4){0.f, 0.f, 0.f, 0.f};
#pragma unroll
      for (int ks = 0; ks < 4; ++ks)
        a = __builtin_amdgcn_mfma_f32_16x16x32_bf16(qf[ks], kfp[i & 1][ks], a, 0, 0, 0);
      int j = wave + 4 * i;
      if (j < 17) {
#pragma unroll
        for (int r = 0; r < 4; ++r) {
          int qrow = g * 4 + r;
          float vv = a[r] * 0.088388347648318447f;   // 1/sqrt(128)
          if (tok_[i] > t * 16 + qrow) vv = -1e10f;  // future mask
          lg[qrow][j * 16 + c] = vv;
        }
      }
    }
  }
  __syncthreads();

  // ---- softmax per q row: row r handled by 16 threads (col = tid&15);
  // bf16 weights written over the row's own f32 storage (reads complete first
  // in lockstep; each wave touches only its own 4 rows).
  {
    const int r = tid >> 4, cc = tid & 15;
    float vals[17];
    float mx = -3.0e38f;
#pragma unroll
    for (int i = 0; i < 17; ++i) { vals[i] = lg[r][i * 16 + cc]; mx = fmaxf(mx, vals[i]); }
#pragma unroll
    for (int d = 1; d < 16; d <<= 1) mx = fmaxf(mx, __shfl_xor(mx, d, 64));
    float sum = 0.f;
#pragma unroll
    for (int i = 0; i < 17; ++i) { vals[i] = __expf(vals[i] - mx); sum += vals[i]; }
#pragma unroll
    for (int d = 1; d < 16; d <<= 1) sum += __shfl_xor(sum, d, 64);
    float inv = sum > 0.f ? 1.0f / sum : 0.f;
    u16* wrow = (u16*)&lg[r][0];
#pragma unroll
    for (int i = 0; i < 17; ++i) wrow[i * 16 + cc] = f2bf(vals[i] * inv);
    wrow[272 + cc] = 0;                        // zero the pad tile's weights
  }
  __syncthreads();

  // ---- PV: out(16x288 . 288x128); wave owns 32 dims; 1-ahead B-pair prefetch
  {
    f32x4 o0 = (f32x4){0.f, 0.f, 0.f, 0.f}, o1 = o0;
    const int d0 = wave * 32;
    const size_t hb = (size_t)h * 256;
    const int keyin = (g & 1) * 8;
    const u16* wrow = (const u16*)&lg[c][0];
    const u16* vb_[9];
#pragma unroll
    for (int ks = 0; ks < 9; ++ks) vb_[ks] = VT2 + (hb + tiles[2 * ks + (g >> 1)]) * 2048;
    bf16x8 pb0[2], pb1[2];
    pb0[0] = *(const bf16x8*)(vb_[0] + (d0 + c) * 16 + keyin);
    pb1[0] = *(const bf16x8*)(vb_[0] + (d0 + 16 + c) * 16 + keyin);
#pragma unroll
    for (int ks = 0; ks < 9; ++ks) {
      if (ks < 8) {
        pb0[(ks + 1) & 1] = *(const bf16x8*)(vb_[ks + 1] + (d0 + c) * 16 + keyin);
        pb1[(ks + 1) & 1] = *(const bf16x8*)(vb_[ks + 1] + (d0 + 16 + c) * 16 + keyin);
      }
      bf16x8 af = *(const bf16x8*)(wrow + ks * 32 + g * 8);
      o0 = __builtin_amdgcn_mfma_f32_16x16x32_bf16(af, pb0[ks & 1], o0, 0, 0, 0);
      o1 = __builtin_amdgcn_mfma_f32_16x16x32_bf16(af, pb1[ks & 1], o1, 0, 0, 0);
    }
#pragma unroll
    for (int r = 0; r < 4; ++r) {
      int qrow = g * 4 + r;
      size_t base = (size_t)(t * 16 + qrow) * 2048 + h * 128;
      Out[base + d0 + c]      = f2bf(o0[r]);
      Out[base + d0 + 16 + c] = f2bf(o1[r]);
    }
  }
}

extern "C" void kernel_launch(void* const* d_in, const int* in_sizes, int n_in,
                              void* d_out, int out_size, void* d_ws, size_t ws_size,
                              hipStream_t stream) {
  (void)in_sizes; (void)n_in; (void)out_size; (void)ws_size;
  const float* x      = (const float*)d_in[0];
  const float* Wq     = (const float*)d_in[1];
  const float* Wk     = (const float*)d_in[2];
  const float* Wv     = (const float*)d_in[3];
  const float* Wo     = (const float*)d_in[4];
  const float* freqs  = (const float*)d_in[5];
  const int* anchors  = (const int*)d_in[6];
  float* out = (float*)d_out;

  char* ws = (char*)d_ws;
  const size_t MB = 1024 * 1024;
  // Layout (98 MB used, aliasing dead buffers):
  //  0..16  : xbf, later attnb (x dead after QKV GEMM)
  // 16..40  : wqkvT contiguous (wqT 16..24, wkT 24..32, wvT 32..40);
  //           later Kp over 16..32 (dead after QKV GEMM)
  // 40..48  : woT (live until final GEMM)
  // 48..64  : qbf
  // 64..80  : kbf; later VT2 (kbf dead after rope writes Kp)
  // 80..96  : vbf
  // 96..98  : ct, st
  u16* xbf   = (u16*)(ws + 0);
  u16* wqkvT = (u16*)(ws + 16 * MB);   // (6144 x 2048) bf16, N x K
  u16* woT   = (u16*)(ws + 40 * MB);
  u16* qbf   = (u16*)(ws + 48 * MB);
  u16* kbf   = (u16*)(ws + 64 * MB);
  u16* vbf   = (u16*)(ws + 80 * MB);
  u16* attnb = (u16*)(ws + 0);
  u16* Kp    = (u16*)(ws + 16 * MB);
  u16* VT2   = (u16*)(ws + 64 * MB);
  float* ct  = (float*)(ws + 96 * MB);
  float* st  = (float*)(ws + 97 * MB);

  // prep1: weight transposes + x cast + trig table (one launch)
  prep1_kernel<<<25600, 256, 0, stream>>>(x, Wq, Wk, Wv, Wo, freqs,
                                          xbf, wqkvT, woT, ct, st);
  // fused QKV projection: C = x(4096x2048) @ WqkvT(6144x2048)^T, routed epilogue
  gemm128_kernel<2><<<dim3(48, 32), 256, 0, stream>>>(xbf, wqkvT, qbf, kbf, vbf,
                                                      4096, 6144, 2048);
  // prep2: RoPE (q in-place, k->Kp) + V repack (one launch)
  prep2_kernel<<<9216, 256, 0, stream>>>(qbf, kbf, Kp, vbf, VT2, ct, st);
  attn_kernel<<<dim3(256, 16), 256, 0, stream>>>(qbf, Kp, VT2, anchors, attnb);
  gemm128_kernel<0><<<dim3(16, 32), 256, 0, stream>>>(attnb, woT, out, nullptr, nullptr,
                                                      4096, 2048, 2048);
}